// Round 18
// baseline (325.863 us; speedup 1.0000x reference)
//
#include <hip/hip_runtime.h>
#include <math.h>
#include <stdint.h>

#define N_NODES 8000
#define N_EDGES 128000
#define NZ 10
#define K 32
#define LDIM 16
#define NB 8
#define NH 32
#define NL 2

typedef _Float16 half8 __attribute__((ext_vector_type(8)));    // 8 f16 (4 VGPR)
typedef _Float16 half2v __attribute__((ext_vector_type(2)));   // packed f16 pair
typedef __attribute__((ext_vector_type(4))) float f32x4;

// wave-level LDS producer->consumer sync
#define WAVE_SYNC() do { \
    asm volatile("s_waitcnt lgkmcnt(0)" ::: "memory"); \
    __builtin_amdgcn_wave_barrier(); \
    __builtin_amdgcn_sched_barrier(0); \
} while (0)

#define NBSTRIDE 640   // per-node LDS buffer: 32 rows x stride 20 (80B rows, 16B-aligned)

// ---------------- rcv histogram ----------------
__global__ __launch_bounds__(256) void k_count(const int* __restrict__ ei,
                                               int* __restrict__ counts) {
    int e = blockIdx.x * 256 + threadIdx.x;
    if (e >= N_EDGES) return;
    atomicAdd(&counts[ei[N_EDGES + e]], 1);
}

// ---------------- exclusive scan of counts -> row_ptr ----------------
__global__ __launch_bounds__(1024) void k_scan(const int* __restrict__ counts,
                                               int* __restrict__ row_ptr,
                                               int* __restrict__ woff) {
    __shared__ int s[8192];
    int tid = threadIdx.x;
    for (int j = tid; j < 8192; j += 1024) s[j] = (j < N_NODES) ? counts[j] : 0;
    __syncthreads();
    for (int off = 1; off < 8192; off <<= 1) {
        int v[8];
#pragma unroll
        for (int jj = 0; jj < 8; jj++) {
            int idx = tid + jj*1024;
            v[jj] = s[idx] + ((idx >= off) ? s[idx - off] : 0);
        }
        __syncthreads();
#pragma unroll
        for (int jj = 0; jj < 8; jj++) s[tid + jj*1024] = v[jj];
        __syncthreads();
    }
    for (int j = tid; j <= N_NODES; j += 1024) {
        int v = (j == 0) ? 0 : s[j-1];
        row_ptr[j] = v;
        if (j < N_NODES) woff[j] = v;
    }
}

// ---------------- scatter: CSR slot per edge (inv) + sender per slot ----------------
__global__ __launch_bounds__(256) void k_scatter(const int* __restrict__ ei,
                                                 int* __restrict__ woff,
                                                 int* __restrict__ inv,
                                                 int* __restrict__ snd_csr) {
    int e = blockIdx.x * 256 + threadIdx.x;
    if (e >= N_EDGES) return;
    int r = ei[N_EDGES + e];
    int s = ei[e];
    int pp = atomicAdd(&woff[r], 1);
    inv[e] = pp;
    snd_csr[pp] = s;
}

// ---------------- edge geometry + C0 + BOTH radial MLPs, CSR slot order ----------------
__global__ __launch_bounds__(256) void k_geom(const float* __restrict__ pos,
                                              const float* __restrict__ shifts,
                                              const int* __restrict__ ei,
                                              const int* __restrict__ inv,
                                              const float* __restrict__ Wcg,
                                              const float* __restrict__ W_r1,
                                              const float* __restrict__ W_r2,
                                              float* __restrict__ Yc,
                                              float* __restrict__ C0c,
                                              float* __restrict__ Rwc0,
                                              float* __restrict__ Rwc1) {
    __shared__ __align__(16) float lW1[2*NB*NH];    // both layers
    __shared__ __align__(16) float lW2[2*NH*K];
    int tid = threadIdx.x;
    for (int j = tid; j < 2*NB*NH; j += 256) lW1[j] = W_r1[j];
    for (int j = tid; j < 2*NH*K;  j += 256) lW2[j] = W_r2[j];
    __syncthreads();

    int e = blockIdx.x * blockDim.x + tid;
    if (e >= N_EDGES) return;
    int snd = ei[e];
    int rcv = ei[N_EDGES + e];
    int slot = inv[e];
    float vx = pos[rcv*3+0] - pos[snd*3+0] + shifts[e*3+0];
    float vy = pos[rcv*3+1] - pos[snd*3+1] + shifts[e*3+1];
    float vz = pos[rcv*3+2] - pos[snd*3+2] + shifts[e*3+2];
    float r2 = vx*vx + vy*vy + vz*vz;
    float r  = sqrtf(fmaxf(r2, 1e-12f));
    float inv_r = 1.0f / r;
    float x = vx*inv_r, y = vy*inv_r, z = vz*inv_r;

    const float s3    = 1.7320508075688772f;
    const float s5    = 2.2360679774997896f;
    const float s15   = 3.8729833462074170f;
    const float s35_8 = 2.0916500663351885f;
    const float s105  = 10.246950765959598f;
    const float s21_8 = 1.6201851746019651f;
    const float s7    = 2.6457513110645907f;

    float Yv[16];
    Yv[0]  = 1.0f;
    Yv[1]  = s3*x;  Yv[2] = s3*y;  Yv[3] = s3*z;
    Yv[4]  = s15*x*y;
    Yv[5]  = s15*y*z;
    Yv[6]  = 0.5f*s5*(3.0f*z*z - 1.0f);
    Yv[7]  = s15*x*z;
    Yv[8]  = 0.5f*s15*(x*x - y*y);
    Yv[9]  = s35_8*y*(3.0f*x*x - y*y);
    Yv[10] = s105*x*y*z;
    Yv[11] = s21_8*y*(5.0f*z*z - 1.0f);
    Yv[12] = 0.5f*s7*(5.0f*z*z*z - 3.0f*z);
    Yv[13] = s21_8*x*(5.0f*z*z - 1.0f);
    Yv[14] = 0.5f*s105*z*(x*x - y*y);
    Yv[15] = s35_8*x*(x*x - 3.0f*y*y);
#pragma unroll
    for (int j = 0; j < 16; j++) Yc[(size_t)slot*16 + j] = Yv[j];

    // C0[t] = sum_s Yv[s] * Wcg[0][s][t]
    {
        float c0[16];
#pragma unroll
        for (int t = 0; t < 16; ++t) c0[t] = 0.0f;
#pragma unroll
        for (int s = 0; s < 16; ++s) {
            const float4* w = (const float4*)(Wcg + s*16);
            float4 w0 = w[0], w1 = w[1], w2 = w[2], w3 = w[3];
            float ys = Yv[s];
            c0[0]+=ys*w0.x;  c0[1]+=ys*w0.y;  c0[2]+=ys*w0.z;  c0[3]+=ys*w0.w;
            c0[4]+=ys*w1.x;  c0[5]+=ys*w1.y;  c0[6]+=ys*w1.z;  c0[7]+=ys*w1.w;
            c0[8]+=ys*w2.x;  c0[9]+=ys*w2.y;  c0[10]+=ys*w2.z; c0[11]+=ys*w2.w;
            c0[12]+=ys*w3.x; c0[13]+=ys*w3.y; c0[14]+=ys*w3.z; c0[15]+=ys*w3.w;
        }
        float* o = C0c + (size_t)slot*16;
#pragma unroll
        for (int tq = 0; tq < 4; ++tq)
            *(float4*)(o + tq*4) = make_float4(c0[tq*4], c0[tq*4+1], c0[tq*4+2], c0[tq*4+3]);
    }

    // radial basis
    float uu = fminf(fmaxf(r * 0.2f, 0.0f), 1.0f);
    float u2 = uu*uu;
    float u6 = u2*u2*u2;
    float f  = 1.0f - 28.0f*u6 + 48.0f*u6*uu - 21.0f*u6*u2;
    float c  = 0.632455532033676f * inv_r * f;
    const float PI5 = 3.14159265358979323846f * 0.2f;
    float efr[8];
#pragma unroll
    for (int n = 1; n <= 8; n++) efr[n-1] = c * sinf((float)n * PI5 * r);

    // both radial MLPs: rw = silu(efr@W1)@W2
#pragma unroll
    for (int L = 0; L < 2; ++L) {
        const float* w1 = lW1 + L*NB*NH;
        const float* w2 = lW2 + L*NH*K;
        float rw[32];
#pragma unroll
        for (int k = 0; k < 32; ++k) rw[k] = 0.0f;
        for (int j = 0; j < NH; ++j) {
            float h = 0.0f;
#pragma unroll
            for (int b = 0; b < NB; ++b) h += efr[b] * w1[b*NH + j];
            float s = h / (1.0f + expf(-h));
            const float4* w2r = (const float4*)(w2 + j*K);
#pragma unroll
            for (int kq = 0; kq < 8; ++kq) {
                float4 w = w2r[kq];
                rw[kq*4+0] += s*w.x; rw[kq*4+1] += s*w.y;
                rw[kq*4+2] += s*w.z; rw[kq*4+3] += s*w.w;
            }
        }
        float* o = (L == 0 ? Rwc0 : Rwc1) + (size_t)slot*32;
#pragma unroll
        for (int kq = 0; kq < 8; ++kq)
            *(float4*)(o + kq*4) = make_float4(rw[kq*4], rw[kq*4+1], rw[kq*4+2], rw[kq*4+3]);
    }
}

// ---------------- WW = W_embed @ W_up0   (Z x K) ----------------
__global__ __launch_bounds__(256) void k_ww(const float* __restrict__ We,
                                            const float* __restrict__ Wup0,
                                            float* __restrict__ WW) {
    int i = blockIdx.x * 256 + threadIdx.x;
    if (i >= NZ * K) return;
    int z = i >> 5, c = i & 31;
    float a = 0.0f;
#pragma unroll
    for (int k = 0; k < K; ++k) a += We[z*K + k] * Wup0[k*K + c];
    WW[i] = a;
}

// ---------------- Wsym[p][t] = Wcg2[a,b,t] (+ Wcg2[b,a,t] for b>a), triangular p ----------------
__global__ __launch_bounds__(256) void k_wsym(const float* __restrict__ Wcg2,
                                              float* __restrict__ Wsym) {
    int j = blockIdx.x * 256 + threadIdx.x;
    if (j >= 136*16) return;
    int p = j >> 4, t = j & 15;
    int a = 0;
    for (int aa = 1; aa < 16; ++aa)
        if (p >= aa*16 - (aa*(aa-1))/2) a = aa;
    int b = a + (p - (a*16 - (a*(a-1))/2));
    float v = Wcg2[a*256 + b*16 + t];
    if (b > a) v += Wcg2[b*256 + a*16 + t];
    Wsym[j] = v;
}

// ---------------- node embedding: feats l=0, compact up0, species ----------------
__global__ __launch_bounds__(256) void k_embed(const float* __restrict__ attrs,
                                               const float* __restrict__ We,
                                               const float* __restrict__ WW,
                                               float* __restrict__ feats,
                                               float* __restrict__ up0c,
                                               int* __restrict__ spec) {
    int i = blockIdx.x * blockDim.x + threadIdx.x;
    if (i >= N_NODES * K) return;
    int n = i >> 5, k = i & 31;
    float a = 0.0f, b = 0.0f;
#pragma unroll
    for (int z = 0; z < NZ; z++) {
        float av = attrs[n*NZ + z];
        a += av * We[z*K + k];
        b += av * WW[z*K + k];
    }
    float* f = feats + (size_t)n*(K*LDIM) + k*LDIM;
    f[0] = a;
#pragma unroll
    for (int j = 1; j < LDIM; j++) f[j] = 0.0f;
    up0c[(size_t)n*K + k] = b;
    if (k == 0) {
        int sp = 0; float best = -1.0f;
        for (int z = 0; z < NZ; z++) { float v = attrs[n*NZ + z]; if (v > best) { best = v; sp = z; } }
        spec[n] = sp;
    }
}

// ---------------- shared node-update phase (wave-per-node; lane = (c, t-half)) ----------------
__device__ __forceinline__ void node_update(float* nb,
                                            const float* lWlin, const float* lWprod,
                                            const float* lWup, const float* lWsym,
                                            const float* __restrict__ Wskip,
                                            float* __restrict__ feats,
                                            const int* __restrict__ spec,
                                            float* __restrict__ out,
                                            int n, int lane, int layer,
                                            _Float16* __restrict__ up_next, int has_up) {
    int c  = lane & 31;
    int th = lane >> 5;
    int to = th * 8;

    // ---- mid8[j] = sum_k agg[k][to+j] * Wlin[k][c] ----
    float m8[8] = {0,0,0,0,0,0,0,0};
#pragma clang loop unroll_count(4)
    for (int k = 0; k < 32; ++k) {
        float w = lWlin[k*32 + c];
        float4 a0 = *(const float4*)(nb + k*20 + to);
        float4 a1 = *(const float4*)(nb + k*20 + to + 4);
        m8[0]+=a0.x*w; m8[1]+=a0.y*w; m8[2]+=a0.z*w; m8[3]+=a0.w*w;
        m8[4]+=a1.x*w; m8[5]+=a1.y*w; m8[6]+=a1.z*w; m8[7]+=a1.w*w;
    }
    WAVE_SYNC();   // all lanes done reading agg rows
    *(float4*)(nb + c*20 + to)     = make_float4(m8[0],m8[1],m8[2],m8[3]);
    *(float4*)(nb + c*20 + to + 4) = make_float4(m8[4],m8[5],m8[6],m8[7]);
    WAVE_SYNC();
    float m[16];
#pragma unroll
    for (int j = 0; j < 4; ++j) {
        float4 v = *(const float4*)(nb + c*20 + j*4);
        m[j*4]=v.x; m[j*4+1]=v.y; m[j*4+2]=v.z; m[j*4+3]=v.w;
    }

    // ---- quad8[j] = sum_{a<=b} m[a]m[b] lWsym[p][to+j]  (m fully in regs) ----
    float q8[8] = {0,0,0,0,0,0,0,0};
    {
        int p = 0;
#pragma clang loop unroll(disable)
        for (int a = 0; a < 16; ++a) {
            float ma = m[a];
#pragma clang loop unroll_count(2)
            for (int b = a; b < 16; ++b) {
                float pm = ma * m[b];
                float4 w0 = *(const float4*)(lWsym + p*16 + to);
                float4 w1 = *(const float4*)(lWsym + p*16 + to + 4);
                q8[0]+=pm*w0.x; q8[1]+=pm*w0.y; q8[2]+=pm*w0.z; q8[3]+=pm*w0.w;
                q8[4]+=pm*w1.x; q8[5]+=pm*w1.y; q8[6]+=pm*w1.z; q8[7]+=pm*w1.w;
                ++p;
            }
        }
    }

    // ---- s = mid + quad -> nb rows ----
    WAVE_SYNC();   // all lanes done reading m rows
    *(float4*)(nb + c*20 + to)     = make_float4(m[to]+q8[0],   m[to+1]+q8[1],
                                                 m[to+2]+q8[2], m[to+3]+q8[3]);
    *(float4*)(nb + c*20 + to + 4) = make_float4(m[to+4]+q8[4], m[to+5]+q8[5],
                                                 m[to+6]+q8[6], m[to+7]+q8[7]);
    WAVE_SYNC();

    // ---- fnew8[j] = sum_k s[k][to+j]*Wprod[k][c] + feats[k][to+j]*Wskip[sp][k][c] ----
    int sp = spec[n];
    const float* wsk = Wskip + (size_t)sp*1024;
    float* fg = feats + (size_t)n*512;
    float acc8[8] = {0,0,0,0,0,0,0,0};
#pragma clang loop unroll_count(4)
    for (int k = 0; k < 32; ++k) {
        float wp = lWprod[k*32 + c];
        float wv = wsk[k*32 + c];
        float4 s0 = *(const float4*)(nb + k*20 + to);
        float4 s1 = *(const float4*)(nb + k*20 + to + 4);
        float4 f0 = *(const float4*)(fg + k*16 + to);
        float4 f1 = *(const float4*)(fg + k*16 + to + 4);
        acc8[0]+=s0.x*wp+f0.x*wv; acc8[1]+=s0.y*wp+f0.y*wv;
        acc8[2]+=s0.z*wp+f0.z*wv; acc8[3]+=s0.w*wp+f0.w*wv;
        acc8[4]+=s1.x*wp+f1.x*wv; acc8[5]+=s1.y*wp+f1.y*wv;
        acc8[6]+=s1.z*wp+f1.z*wv; acc8[7]+=s1.w*wp+f1.w*wv;
    }
    if (th == 0) out[(size_t)n*(NL*K) + layer*K + c] = acc8[0];
    *(float4*)(fg + c*16 + to)     = make_float4(acc8[0],acc8[1],acc8[2],acc8[3]);
    *(float4*)(fg + c*16 + to + 4) = make_float4(acc8[4],acc8[5],acc8[6],acc8[7]);

    if (has_up) {
        // fnew -> nb rows, then up8[j] = sum_k fnew[k][to+j] * Wup[k][c]
        WAVE_SYNC();   // all lanes done reading s rows
        *(float4*)(nb + c*20 + to)     = make_float4(acc8[0],acc8[1],acc8[2],acc8[3]);
        *(float4*)(nb + c*20 + to + 4) = make_float4(acc8[4],acc8[5],acc8[6],acc8[7]);
        WAVE_SYNC();
        float u8[8] = {0,0,0,0,0,0,0,0};
#pragma clang loop unroll_count(4)
        for (int k = 0; k < 32; ++k) {
            float w = lWup[k*32 + c];
            float4 f0 = *(const float4*)(nb + k*20 + to);
            float4 f1 = *(const float4*)(nb + k*20 + to + 4);
            u8[0]+=f0.x*w; u8[1]+=f0.y*w; u8[2]+=f0.z*w; u8[3]+=f0.w*w;
            u8[4]+=f1.x*w; u8[5]+=f1.y*w; u8[6]+=f1.z*w; u8[7]+=f1.w*w;
        }
        half8 h;
#pragma unroll
        for (int j = 0; j < 8; ++j) h[j] = (_Float16)u8[j];
        *(half8*)(up_next + (size_t)n*512 + c*16 + to) = h;
    }
}

// ---------------- layer 0 fused: rank-1 aggregation (precomputed C0) + node update ----------------
__global__ __launch_bounds__(256, 4) void k_fused0(const float* __restrict__ up0c,
                                                   const float* __restrict__ C0c,
                                                   const float* __restrict__ Rwc,
                                                   const int* __restrict__ snd_csr,
                                                   const int* __restrict__ row_ptr,
                                                   const float* __restrict__ Wlin,
                                                   const float* __restrict__ Wskip,
                                                   const float* __restrict__ Wprod,
                                                   const float* __restrict__ WsymG,
                                                   const float* __restrict__ Wup_next,
                                                   float* __restrict__ feats,
                                                   const int* __restrict__ spec,
                                                   float* __restrict__ out,
                                                   _Float16* __restrict__ up_next) {
    __shared__ __align__(16) float lWlin[1024];
    __shared__ __align__(16) float lWprod[1024];
    __shared__ __align__(16) float lWup[1024];
    __shared__ __align__(16) float lWsym[2176];
    __shared__ __align__(16) float buf[4*NBSTRIDE];

    int tid = threadIdx.x;
    for (int j = tid; j < 1024; j += 256) { lWlin[j] = Wlin[j]; lWprod[j] = Wprod[j]; lWup[j] = Wup_next[j]; }
    for (int j = tid; j < 2176; j += 256) lWsym[j] = WsymG[j];
    __syncthreads();

    int wave = tid >> 6, lane = tid & 63;
    int n = blockIdx.x * 4 + wave;
    int k0 = lane & 15, tq = lane >> 4;
    float* nb = buf + wave*NBSTRIDE;

    int start = row_ptr[n], end = row_ptr[n+1];
    float4 acc0 = {0,0,0,0}, acc1 = {0,0,0,0};

    if (start < end) {
        int snd = snd_csr[start];
        float4 c0v = *(const float4*)(C0c + (size_t)start*16 + tq*4);
        float rw0 = Rwc[(size_t)start*32 + k0];
        float rw1 = Rwc[(size_t)start*32 + 16 + k0];
        float u0 = up0c[(size_t)snd*32 + k0];
        float u1 = up0c[(size_t)snd*32 + 16 + k0];

        for (int ii = start; ii < end; ++ii) {
            int ip = (ii + 1 < end) ? ii + 1 : ii;
            int nsnd = snd_csr[ip];
            float4 nc0v = *(const float4*)(C0c + (size_t)ip*16 + tq*4);
            float nrw0 = Rwc[(size_t)ip*32 + k0];
            float nrw1 = Rwc[(size_t)ip*32 + 16 + k0];
            float nu0 = up0c[(size_t)nsnd*32 + k0];
            float nu1 = up0c[(size_t)nsnd*32 + 16 + k0];

            float g0 = rw0 * u0, g1 = rw1 * u1;
            acc0.x += g0*c0v.x; acc0.y += g0*c0v.y; acc0.z += g0*c0v.z; acc0.w += g0*c0v.w;
            acc1.x += g1*c0v.x; acc1.y += g1*c0v.y; acc1.z += g1*c0v.z; acc1.w += g1*c0v.w;

            c0v = nc0v; rw0 = nrw0; rw1 = nrw1; u0 = nu0; u1 = nu1;
        }
    }

    // agg -> nb rows (k0 covers rows k0 and 16+k0; cols tq*4..tq*4+3)
    *(float4*)(nb + k0*20 + tq*4)      = make_float4(acc0.x*0.0625f, acc0.y*0.0625f,
                                                     acc0.z*0.0625f, acc0.w*0.0625f);
    *(float4*)(nb + (16+k0)*20 + tq*4) = make_float4(acc1.x*0.0625f, acc1.y*0.0625f,
                                                     acc1.z*0.0625f, acc1.w*0.0625f);
    WAVE_SYNC();

    node_update(nb, lWlin, lWprod, lWup, lWsym, Wskip, feats, spec, out, n, lane, 0, up_next, 1);
}

// ---------------- layer 1 fused: fp16 MFMA aggregation (packed-f16 phase A) + node update ----------------
__global__ __launch_bounds__(256, 4) void k_fused1(const _Float16* __restrict__ up,
                                                   const float* __restrict__ Yc,
                                                   const float* __restrict__ Rwc,
                                                   const int* __restrict__ snd_csr,
                                                   const int* __restrict__ row_ptr,
                                                   const float* __restrict__ Wcg,
                                                   const float* __restrict__ Wlin,
                                                   const float* __restrict__ Wskip,
                                                   const float* __restrict__ Wprod,
                                                   const float* __restrict__ WsymG,
                                                   float* __restrict__ feats,
                                                   const int* __restrict__ spec,
                                                   float* __restrict__ out) {
    __shared__ __align__(16) float lWlin[1024];
    __shared__ __align__(16) float lWprod[1024];
    __shared__ __align__(16) float lWsym[2176];
    __shared__ __align__(16) float buf[4*NBSTRIDE];

    int tid = threadIdx.x;
    for (int j = tid; j < 1024; j += 256) { lWlin[j] = Wlin[j]; lWprod[j] = Wprod[j]; }
    for (int j = tid; j < 2176; j += 256) lWsym[j] = WsymG[j];
    __syncthreads();

    int wave = tid >> 6, lane = tid & 63;
    int n = blockIdx.x * 4 + wave;
    int t0 = lane & 15;
    int g  = lane >> 4;
    int h  = g & 1;
    int eo = g >> 1;
    float* nb = buf + wave*NBSTRIDE;

    // per-lane Wcg slice packed f16: wrh[s][q] = {Wcg[8h+2q][s][t0], Wcg[8h+2q+1][s][t0]}  (32 VGPR)
    half2v wrh[16][4];
#pragma unroll
    for (int s = 0; s < 16; ++s)
#pragma unroll
        for (int q = 0; q < 4; ++q) {
            half2v w;
            w[0] = (_Float16)Wcg[(8*h + 2*q    )*256 + s*16 + t0];
            w[1] = (_Float16)Wcg[(8*h + 2*q + 1)*256 + s*16 + t0];
            wrh[s][q] = w;
        }

    int start = row_ptr[n], end = row_ptr[n+1];
    f32x4 accL = {0.f,0.f,0.f,0.f}, accH = {0.f,0.f,0.f,0.f};

    if (start < end) {
        int i0 = start + eo;     bool v0 = i0 < end; int q0 = v0 ? i0 : start;
        int i1 = i0 + 2;         bool v1 = i1 < end; int q1 = v1 ? i1 : start;
        int i2 = i0 + 4;         bool v2 = i2 < end; int q2 = v2 ? i2 : start;
        int snd0 = snd_csr[q0], snd1 = snd_csr[q1];
        int snd2 = snd_csr[q2];

        const float4* Y4 = (const float4*)(Yc + (size_t)q0*16);
        float4 y0=Y4[0], y1=Y4[1], y2=Y4[2], y3=Y4[3];
        float rwL = v0 ? Rwc[(size_t)q0*32 + t0]      : 0.0f;
        float rwH = v0 ? Rwc[(size_t)q0*32 + 16 + t0] : 0.0f;
        half8 u0L = *(const half8*)(up + (size_t)snd0*512 + t0*16 + 8*h);
        half8 u0H = *(const half8*)(up + (size_t)snd0*512 + (16+t0)*16 + 8*h);
        half8 u1L = *(const half8*)(up + (size_t)snd1*512 + t0*16 + 8*h);
        half8 u1H = *(const half8*)(up + (size_t)snd1*512 + (16+t0)*16 + 8*h);

        int npair = (end - start + 1) >> 1;
        for (int p = 0; p < npair; ++p) {
            half8 u2L = *(const half8*)(up + (size_t)snd2*512 + t0*16 + 8*h);
            half8 u2H = *(const half8*)(up + (size_t)snd2*512 + (16+t0)*16 + 8*h);
            int in1 = start + 2*(p+1) + eo; bool vn1 = in1 < end; int qn1 = vn1 ? in1 : start;
            const float4* nY = (const float4*)(Yc + (size_t)qn1*16);
            float4 ny0=nY[0], ny1=nY[1], ny2=nY[2], ny3=nY[3];
            float nrwL = vn1 ? Rwc[(size_t)qn1*32 + t0]      : 0.0f;
            float nrwH = vn1 ? Rwc[(size_t)qn1*32 + 16 + t0] : 0.0f;
            int in3 = start + 2*(p+3) + eo; bool vn3 = in3 < end; int qn3 = vn3 ? in3 : start;
            int snd3 = snd_csr[qn3];

            // ---- phase A packed f16: ch[q] = sum_s (f16)y[s] * wrh[s][q] ----
            float yv[16] = {y0.x,y0.y,y0.z,y0.w, y1.x,y1.y,y1.z,y1.w,
                            y2.x,y2.y,y2.z,y2.w, y3.x,y3.y,y3.z,y3.w};
            half2v ch[4];
#pragma unroll
            for (int q = 0; q < 4; ++q) { half2v z; z[0]=(_Float16)0.f; z[1]=(_Float16)0.f; ch[q]=z; }
#pragma unroll
            for (int s = 0; s < 16; ++s) {
                _Float16 yh = (_Float16)yv[s];
                half2v yb; yb[0] = yh; yb[1] = yh;
#pragma unroll
                for (int q = 0; q < 4; ++q) ch[q] += yb * wrh[s][q];
            }
            half8 bf;
#pragma unroll
            for (int q = 0; q < 4; ++q) { bf[2*q] = ch[q][0]; bf[2*q+1] = ch[q][1]; }

            half8 rvL, rvH;
            _Float16 rwLh = (_Float16)rwL, rwHh = (_Float16)rwH;
#pragma unroll
            for (int j = 0; j < 8; ++j) { rvL[j] = rwLh; rvH[j] = rwHh; }
            half8 afL = u0L * rvL;
            half8 afH = u0H * rvH;

            accL = __builtin_amdgcn_mfma_f32_16x16x32_f16(afL, bf, accL, 0, 0, 0);
            accH = __builtin_amdgcn_mfma_f32_16x16x32_f16(afH, bf, accH, 0, 0, 0);

            y0=ny0; y1=ny1; y2=ny2; y3=ny3;
            rwL=nrwL; rwH=nrwH;
            u0L=u1L; u0H=u1H; u1L=u2L; u1H=u2H;
            snd2 = snd3;
        }
    }

    // agg (MFMA D layout) -> nb rows: D row i=4g+e, col t0
#pragma unroll
    for (int e = 0; e < 4; ++e) {
        nb[(4*g + e)*20 + t0]      = accL[e] * 0.0625f;
        nb[(16 + 4*g + e)*20 + t0] = accH[e] * 0.0625f;
    }
    WAVE_SYNC();

    node_update(nb, lWlin, lWprod, (const float*)nullptr, lWsym, Wskip, feats, spec, out,
                n, lane, 1, (_Float16*)nullptr, 0);
}

extern "C" void kernel_launch(void* const* d_in, const int* in_sizes, int n_in,
                              void* d_out, int out_size, void* d_ws, size_t ws_size,
                              hipStream_t stream) {
    const float* pos     = (const float*)d_in[0];
    const float* shifts  = (const float*)d_in[1];
    const float* attrs   = (const float*)d_in[2];
    const float* W_embed = (const float*)d_in[3];
    const float* W_up    = (const float*)d_in[4];
    const float* W_r1    = (const float*)d_in[5];
    const float* W_r2    = (const float*)d_in[6];
    const float* W_lin   = (const float*)d_in[7];
    const float* W_skip  = (const float*)d_in[8];
    const float* W_prod  = (const float*)d_in[9];
    const float* Wcg     = (const float*)d_in[10];
    const float* Wcg2    = (const float*)d_in[11];
    const int*   ei      = (const int*)d_in[12];
    float* out = (float*)d_out;

    uint8_t* p = (uint8_t*)d_ws;
    auto alloc = [&](size_t bytes) -> void* {
        void* r = (void*)p;
        p += (bytes + 255) & ~size_t(255);
        return r;
    };
    float* Yc        = (float*)alloc((size_t)N_EDGES * 16 * sizeof(float));
    float* C0c       = (float*)alloc((size_t)N_EDGES * 16 * sizeof(float));
    float* Rwc0      = (float*)alloc((size_t)N_EDGES * K  * sizeof(float));
    float* Rwc1      = (float*)alloc((size_t)N_EDGES * K  * sizeof(float));
    float* feats     = (float*)alloc((size_t)N_NODES * K * LDIM * sizeof(float));
    _Float16* up_h   = (_Float16*)alloc((size_t)N_NODES * K * LDIM * sizeof(_Float16));
    float* up0c      = (float*)alloc((size_t)N_NODES * K * sizeof(float));
    float* WW        = (float*)alloc((size_t)NZ * K * sizeof(float));
    float* Wsym      = (float*)alloc((size_t)136 * 16 * sizeof(float));
    int* counts   = (int*)alloc((size_t)N_NODES * sizeof(int));
    int* woff     = (int*)alloc((size_t)N_NODES * sizeof(int));
    int* row_ptr  = (int*)alloc((size_t)(N_NODES + 1) * sizeof(int));
    int* inv      = (int*)alloc((size_t)N_EDGES * sizeof(int));
    int* snd_csr  = (int*)alloc((size_t)N_EDGES * sizeof(int));
    int* spec     = (int*)alloc((size_t)N_NODES * sizeof(int));

    hipMemsetAsync(counts, 0, N_NODES * sizeof(int), stream);
    k_count<<<(N_EDGES + 255) / 256, 256, 0, stream>>>(ei, counts);
    k_scan<<<1, 1024, 0, stream>>>(counts, row_ptr, woff);
    k_scatter<<<(N_EDGES + 255) / 256, 256, 0, stream>>>(ei, woff, inv, snd_csr);
    k_geom<<<(N_EDGES + 255) / 256, 256, 0, stream>>>(pos, shifts, ei, inv, Wcg,
                                                      W_r1, W_r2, Yc, C0c, Rwc0, Rwc1);
    k_ww<<<2, 256, 0, stream>>>(W_embed, W_up, WW);
    k_wsym<<<(136*16 + 255) / 256, 256, 0, stream>>>(Wcg2, Wsym);
    k_embed<<<(N_NODES * K + 255) / 256, 256, 0, stream>>>(attrs, W_embed, WW, feats, up0c, spec);

    // layer 0 fused (writes out[:,0:32], feats, up_h for layer 1)
    k_fused0<<<N_NODES/4, 256, 0, stream>>>(up0c, C0c, Rwc0, snd_csr, row_ptr,
                                            W_lin, W_skip, W_prod, Wsym,
                                            W_up + (size_t)1*K*K,
                                            feats, spec, out, up_h);

    // layer 1 fused (writes out[:,32:64], feats)
    k_fused1<<<N_NODES/4, 256, 0, stream>>>(up_h, Yc, Rwc1, snd_csr, row_ptr, Wcg,
                                            W_lin + (size_t)1*K*K,
                                            W_skip + (size_t)1*NZ*K*K,
                                            W_prod + (size_t)1*K*K, Wsym,
                                            feats, spec, out);
}

// Round 19
// 225.208 us; speedup vs baseline: 1.4469x; 1.4469x over previous
//
#include <hip/hip_runtime.h>
#include <math.h>
#include <stdint.h>

#define N_NODES 8000
#define N_EDGES 128000
#define NZ 10
#define K 32
#define LDIM 16
#define NB 8
#define NH 32
#define NL 2

typedef _Float16 half8 __attribute__((ext_vector_type(8)));    // 8 f16 (4 VGPR)
typedef _Float16 half2v __attribute__((ext_vector_type(2)));   // packed f16 pair
typedef __attribute__((ext_vector_type(4))) float f32x4;

// wave-level LDS producer->consumer sync
#define WAVE_SYNC() do { \
    asm volatile("s_waitcnt lgkmcnt(0)" ::: "memory"); \
    __builtin_amdgcn_wave_barrier(); \
    __builtin_amdgcn_sched_barrier(0); \
} while (0)

#define NBSTRIDE 640   // per-node LDS buffer: 32 rows x stride 20 (80B rows, 16B-aligned)

// ---------------- rcv histogram ----------------
__global__ __launch_bounds__(256) void k_count(const int* __restrict__ ei,
                                               int* __restrict__ counts) {
    int e = blockIdx.x * 256 + threadIdx.x;
    if (e >= N_EDGES) return;
    atomicAdd(&counts[ei[N_EDGES + e]], 1);
}

// ---------------- exclusive scan of counts -> row_ptr ----------------
__global__ __launch_bounds__(1024) void k_scan(const int* __restrict__ counts,
                                               int* __restrict__ row_ptr,
                                               int* __restrict__ woff) {
    __shared__ int s[8192];
    int tid = threadIdx.x;
    for (int j = tid; j < 8192; j += 1024) s[j] = (j < N_NODES) ? counts[j] : 0;
    __syncthreads();
    for (int off = 1; off < 8192; off <<= 1) {
        int v[8];
#pragma unroll
        for (int jj = 0; jj < 8; jj++) {
            int idx = tid + jj*1024;
            v[jj] = s[idx] + ((idx >= off) ? s[idx - off] : 0);
        }
        __syncthreads();
#pragma unroll
        for (int jj = 0; jj < 8; jj++) s[tid + jj*1024] = v[jj];
        __syncthreads();
    }
    for (int j = tid; j <= N_NODES; j += 1024) {
        int v = (j == 0) ? 0 : s[j-1];
        row_ptr[j] = v;
        if (j < N_NODES) woff[j] = v;
    }
}

// ---------------- scatter: CSR slot per edge (inv) + sender per slot ----------------
__global__ __launch_bounds__(256) void k_scatter(const int* __restrict__ ei,
                                                 int* __restrict__ woff,
                                                 int* __restrict__ inv,
                                                 int* __restrict__ snd_csr) {
    int e = blockIdx.x * 256 + threadIdx.x;
    if (e >= N_EDGES) return;
    int r = ei[N_EDGES + e];
    int s = ei[e];
    int pp = atomicAdd(&woff[r], 1);
    inv[e] = pp;
    snd_csr[pp] = s;
}

// ---------------- edge geometry + C0 + BOTH radial MLPs, CSR slot order ----------------
__global__ __launch_bounds__(256) void k_geom(const float* __restrict__ pos,
                                              const float* __restrict__ shifts,
                                              const int* __restrict__ ei,
                                              const int* __restrict__ inv,
                                              const float* __restrict__ Wcg,
                                              const float* __restrict__ W_r1,
                                              const float* __restrict__ W_r2,
                                              float* __restrict__ Yc,
                                              float* __restrict__ C0c,
                                              float* __restrict__ Rwc0,
                                              float* __restrict__ Rwc1) {
    __shared__ __align__(16) float lW1[2*NB*NH];    // both layers
    __shared__ __align__(16) float lW2[2*NH*K];
    int tid = threadIdx.x;
    for (int j = tid; j < 2*NB*NH; j += 256) lW1[j] = W_r1[j];
    for (int j = tid; j < 2*NH*K;  j += 256) lW2[j] = W_r2[j];
    __syncthreads();

    int e = blockIdx.x * blockDim.x + tid;
    if (e >= N_EDGES) return;
    int snd = ei[e];
    int rcv = ei[N_EDGES + e];
    int slot = inv[e];
    float vx = pos[rcv*3+0] - pos[snd*3+0] + shifts[e*3+0];
    float vy = pos[rcv*3+1] - pos[snd*3+1] + shifts[e*3+1];
    float vz = pos[rcv*3+2] - pos[snd*3+2] + shifts[e*3+2];
    float r2 = vx*vx + vy*vy + vz*vz;
    float r  = sqrtf(fmaxf(r2, 1e-12f));
    float inv_r = 1.0f / r;
    float x = vx*inv_r, y = vy*inv_r, z = vz*inv_r;

    const float s3    = 1.7320508075688772f;
    const float s5    = 2.2360679774997896f;
    const float s15   = 3.8729833462074170f;
    const float s35_8 = 2.0916500663351885f;
    const float s105  = 10.246950765959598f;
    const float s21_8 = 1.6201851746019651f;
    const float s7    = 2.6457513110645907f;

    float Yv[16];
    Yv[0]  = 1.0f;
    Yv[1]  = s3*x;  Yv[2] = s3*y;  Yv[3] = s3*z;
    Yv[4]  = s15*x*y;
    Yv[5]  = s15*y*z;
    Yv[6]  = 0.5f*s5*(3.0f*z*z - 1.0f);
    Yv[7]  = s15*x*z;
    Yv[8]  = 0.5f*s15*(x*x - y*y);
    Yv[9]  = s35_8*y*(3.0f*x*x - y*y);
    Yv[10] = s105*x*y*z;
    Yv[11] = s21_8*y*(5.0f*z*z - 1.0f);
    Yv[12] = 0.5f*s7*(5.0f*z*z*z - 3.0f*z);
    Yv[13] = s21_8*x*(5.0f*z*z - 1.0f);
    Yv[14] = 0.5f*s105*z*(x*x - y*y);
    Yv[15] = s35_8*x*(x*x - 3.0f*y*y);
#pragma unroll
    for (int j = 0; j < 16; j++) Yc[(size_t)slot*16 + j] = Yv[j];

    // C0[t] = sum_s Yv[s] * Wcg[0][s][t]
    {
        float c0[16];
#pragma unroll
        for (int t = 0; t < 16; ++t) c0[t] = 0.0f;
#pragma unroll
        for (int s = 0; s < 16; ++s) {
            const float4* w = (const float4*)(Wcg + s*16);
            float4 w0 = w[0], w1 = w[1], w2 = w[2], w3 = w[3];
            float ys = Yv[s];
            c0[0]+=ys*w0.x;  c0[1]+=ys*w0.y;  c0[2]+=ys*w0.z;  c0[3]+=ys*w0.w;
            c0[4]+=ys*w1.x;  c0[5]+=ys*w1.y;  c0[6]+=ys*w1.z;  c0[7]+=ys*w1.w;
            c0[8]+=ys*w2.x;  c0[9]+=ys*w2.y;  c0[10]+=ys*w2.z; c0[11]+=ys*w2.w;
            c0[12]+=ys*w3.x; c0[13]+=ys*w3.y; c0[14]+=ys*w3.z; c0[15]+=ys*w3.w;
        }
        float* o = C0c + (size_t)slot*16;
#pragma unroll
        for (int tq = 0; tq < 4; ++tq)
            *(float4*)(o + tq*4) = make_float4(c0[tq*4], c0[tq*4+1], c0[tq*4+2], c0[tq*4+3]);
    }

    // radial basis
    float uu = fminf(fmaxf(r * 0.2f, 0.0f), 1.0f);
    float u2 = uu*uu;
    float u6 = u2*u2*u2;
    float f  = 1.0f - 28.0f*u6 + 48.0f*u6*uu - 21.0f*u6*u2;
    float c  = 0.632455532033676f * inv_r * f;
    const float PI5 = 3.14159265358979323846f * 0.2f;
    float efr[8];
#pragma unroll
    for (int n = 1; n <= 8; n++) efr[n-1] = c * sinf((float)n * PI5 * r);

    // both radial MLPs: rw = silu(efr@W1)@W2
#pragma unroll
    for (int L = 0; L < 2; ++L) {
        const float* w1 = lW1 + L*NB*NH;
        const float* w2 = lW2 + L*NH*K;
        float rw[32];
#pragma unroll
        for (int k = 0; k < 32; ++k) rw[k] = 0.0f;
        for (int j = 0; j < NH; ++j) {
            float h = 0.0f;
#pragma unroll
            for (int b = 0; b < NB; ++b) h += efr[b] * w1[b*NH + j];
            float s = h / (1.0f + expf(-h));
            const float4* w2r = (const float4*)(w2 + j*K);
#pragma unroll
            for (int kq = 0; kq < 8; ++kq) {
                float4 w = w2r[kq];
                rw[kq*4+0] += s*w.x; rw[kq*4+1] += s*w.y;
                rw[kq*4+2] += s*w.z; rw[kq*4+3] += s*w.w;
            }
        }
        float* o = (L == 0 ? Rwc0 : Rwc1) + (size_t)slot*32;
#pragma unroll
        for (int kq = 0; kq < 8; ++kq)
            *(float4*)(o + kq*4) = make_float4(rw[kq*4], rw[kq*4+1], rw[kq*4+2], rw[kq*4+3]);
    }
}

// ---------------- WW = W_embed @ W_up0   (Z x K) ----------------
__global__ __launch_bounds__(256) void k_ww(const float* __restrict__ We,
                                            const float* __restrict__ Wup0,
                                            float* __restrict__ WW) {
    int i = blockIdx.x * 256 + threadIdx.x;
    if (i >= NZ * K) return;
    int z = i >> 5, c = i & 31;
    float a = 0.0f;
#pragma unroll
    for (int k = 0; k < K; ++k) a += We[z*K + k] * Wup0[k*K + c];
    WW[i] = a;
}

// ---------------- Wsym[p][t] = Wcg2[a,b,t] (+ Wcg2[b,a,t] for b>a), triangular p ----------------
__global__ __launch_bounds__(256) void k_wsym(const float* __restrict__ Wcg2,
                                              float* __restrict__ Wsym) {
    int j = blockIdx.x * 256 + threadIdx.x;
    if (j >= 136*16) return;
    int p = j >> 4, t = j & 15;
    int a = 0;
    for (int aa = 1; aa < 16; ++aa)
        if (p >= aa*16 - (aa*(aa-1))/2) a = aa;
    int b = a + (p - (a*16 - (a*(a-1))/2));
    float v = Wcg2[a*256 + b*16 + t];
    if (b > a) v += Wcg2[b*256 + a*16 + t];
    Wsym[j] = v;
}

// ---------------- node embedding: feats l=0, compact up0, species ----------------
__global__ __launch_bounds__(256) void k_embed(const float* __restrict__ attrs,
                                               const float* __restrict__ We,
                                               const float* __restrict__ WW,
                                               float* __restrict__ feats,
                                               float* __restrict__ up0c,
                                               int* __restrict__ spec) {
    int i = blockIdx.x * blockDim.x + threadIdx.x;
    if (i >= N_NODES * K) return;
    int n = i >> 5, k = i & 31;
    float a = 0.0f, b = 0.0f;
#pragma unroll
    for (int z = 0; z < NZ; z++) {
        float av = attrs[n*NZ + z];
        a += av * We[z*K + k];
        b += av * WW[z*K + k];
    }
    float* f = feats + (size_t)n*(K*LDIM) + k*LDIM;
    f[0] = a;
#pragma unroll
    for (int j = 1; j < LDIM; j++) f[j] = 0.0f;
    up0c[(size_t)n*K + k] = b;
    if (k == 0) {
        int sp = 0; float best = -1.0f;
        for (int z = 0; z < NZ; z++) { float v = attrs[n*NZ + z]; if (v > best) { best = v; sp = z; } }
        spec[n] = sp;
    }
}

// ---------------- shared node-update phase (wave-per-node; lane = (c, t-half)) ----------------
__device__ __forceinline__ void node_update(float* nb,
                                            const float* lWlin, const float* lWprod,
                                            const float* lWup, const float* lWsym,
                                            const float* __restrict__ Wskip,
                                            float* __restrict__ feats,
                                            const int* __restrict__ spec,
                                            float* __restrict__ out,
                                            int n, int lane, int layer,
                                            _Float16* __restrict__ up_next, int has_up) {
    int c  = lane & 31;
    int th = lane >> 5;
    int to = th * 8;

    // ---- mid8[j] = sum_k agg[k][to+j] * Wlin[k][c] ----
    float m8[8] = {0,0,0,0,0,0,0,0};
#pragma clang loop unroll_count(4)
    for (int k = 0; k < 32; ++k) {
        float w = lWlin[k*32 + c];
        float4 a0 = *(const float4*)(nb + k*20 + to);
        float4 a1 = *(const float4*)(nb + k*20 + to + 4);
        m8[0]+=a0.x*w; m8[1]+=a0.y*w; m8[2]+=a0.z*w; m8[3]+=a0.w*w;
        m8[4]+=a1.x*w; m8[5]+=a1.y*w; m8[6]+=a1.z*w; m8[7]+=a1.w*w;
    }
    WAVE_SYNC();   // all lanes done reading agg rows
    *(float4*)(nb + c*20 + to)     = make_float4(m8[0],m8[1],m8[2],m8[3]);
    *(float4*)(nb + c*20 + to + 4) = make_float4(m8[4],m8[5],m8[6],m8[7]);
    WAVE_SYNC();
    float m[16];
#pragma unroll
    for (int j = 0; j < 4; ++j) {
        float4 v = *(const float4*)(nb + c*20 + j*4);
        m[j*4]=v.x; m[j*4+1]=v.y; m[j*4+2]=v.z; m[j*4+3]=v.w;
    }

    // ---- quad8[j] = sum_{a<=b} m[a]m[b] lWsym[p][to+j]  (m fully in regs) ----
    float q8[8] = {0,0,0,0,0,0,0,0};
    {
        int p = 0;
#pragma clang loop unroll(disable)
        for (int a = 0; a < 16; ++a) {
            float ma = m[a];
#pragma clang loop unroll_count(2)
            for (int b = a; b < 16; ++b) {
                float pm = ma * m[b];
                float4 w0 = *(const float4*)(lWsym + p*16 + to);
                float4 w1 = *(const float4*)(lWsym + p*16 + to + 4);
                q8[0]+=pm*w0.x; q8[1]+=pm*w0.y; q8[2]+=pm*w0.z; q8[3]+=pm*w0.w;
                q8[4]+=pm*w1.x; q8[5]+=pm*w1.y; q8[6]+=pm*w1.z; q8[7]+=pm*w1.w;
                ++p;
            }
        }
    }

    // ---- s = mid + quad -> nb rows ----
    WAVE_SYNC();   // all lanes done reading m rows
    *(float4*)(nb + c*20 + to)     = make_float4(m[to]+q8[0],   m[to+1]+q8[1],
                                                 m[to+2]+q8[2], m[to+3]+q8[3]);
    *(float4*)(nb + c*20 + to + 4) = make_float4(m[to+4]+q8[4], m[to+5]+q8[5],
                                                 m[to+6]+q8[6], m[to+7]+q8[7]);
    WAVE_SYNC();

    // ---- fnew8[j] = sum_k s[k][to+j]*Wprod[k][c] + feats[k][to+j]*Wskip[sp][k][c] ----
    int sp = spec[n];
    const float* wsk = Wskip + (size_t)sp*1024;
    float* fg = feats + (size_t)n*512;
    float acc8[8] = {0,0,0,0,0,0,0,0};
#pragma clang loop unroll_count(4)
    for (int k = 0; k < 32; ++k) {
        float wp = lWprod[k*32 + c];
        float wv = wsk[k*32 + c];
        float4 s0 = *(const float4*)(nb + k*20 + to);
        float4 s1 = *(const float4*)(nb + k*20 + to + 4);
        float4 f0 = *(const float4*)(fg + k*16 + to);
        float4 f1 = *(const float4*)(fg + k*16 + to + 4);
        acc8[0]+=s0.x*wp+f0.x*wv; acc8[1]+=s0.y*wp+f0.y*wv;
        acc8[2]+=s0.z*wp+f0.z*wv; acc8[3]+=s0.w*wp+f0.w*wv;
        acc8[4]+=s1.x*wp+f1.x*wv; acc8[5]+=s1.y*wp+f1.y*wv;
        acc8[6]+=s1.z*wp+f1.z*wv; acc8[7]+=s1.w*wp+f1.w*wv;
    }
    if (th == 0) out[(size_t)n*(NL*K) + layer*K + c] = acc8[0];
    *(float4*)(fg + c*16 + to)     = make_float4(acc8[0],acc8[1],acc8[2],acc8[3]);
    *(float4*)(fg + c*16 + to + 4) = make_float4(acc8[4],acc8[5],acc8[6],acc8[7]);

    if (has_up) {
        // fnew -> nb rows, then up8[j] = sum_k fnew[k][to+j] * Wup[k][c]
        WAVE_SYNC();   // all lanes done reading s rows
        *(float4*)(nb + c*20 + to)     = make_float4(acc8[0],acc8[1],acc8[2],acc8[3]);
        *(float4*)(nb + c*20 + to + 4) = make_float4(acc8[4],acc8[5],acc8[6],acc8[7]);
        WAVE_SYNC();
        float u8[8] = {0,0,0,0,0,0,0,0};
#pragma clang loop unroll_count(4)
        for (int k = 0; k < 32; ++k) {
            float w = lWup[k*32 + c];
            float4 f0 = *(const float4*)(nb + k*20 + to);
            float4 f1 = *(const float4*)(nb + k*20 + to + 4);
            u8[0]+=f0.x*w; u8[1]+=f0.y*w; u8[2]+=f0.z*w; u8[3]+=f0.w*w;
            u8[4]+=f1.x*w; u8[5]+=f1.y*w; u8[6]+=f1.z*w; u8[7]+=f1.w*w;
        }
        half8 h;
#pragma unroll
        for (int j = 0; j < 8; ++j) h[j] = (_Float16)u8[j];
        *(half8*)(up_next + (size_t)n*512 + c*16 + to) = h;
    }
}

// ---------------- layer 0 fused: rank-1 aggregation (precomputed C0) + node update ----------------
__global__ __launch_bounds__(256, 4) void k_fused0(const float* __restrict__ up0c,
                                                   const float* __restrict__ C0c,
                                                   const float* __restrict__ Rwc,
                                                   const int* __restrict__ snd_csr,
                                                   const int* __restrict__ row_ptr,
                                                   const float* __restrict__ Wlin,
                                                   const float* __restrict__ Wskip,
                                                   const float* __restrict__ Wprod,
                                                   const float* __restrict__ WsymG,
                                                   const float* __restrict__ Wup_next,
                                                   float* __restrict__ feats,
                                                   const int* __restrict__ spec,
                                                   float* __restrict__ out,
                                                   _Float16* __restrict__ up_next) {
    __shared__ __align__(16) float lWlin[1024];
    __shared__ __align__(16) float lWprod[1024];
    __shared__ __align__(16) float lWup[1024];
    __shared__ __align__(16) float lWsym[2176];
    __shared__ __align__(16) float buf[4*NBSTRIDE];

    int tid = threadIdx.x;
    for (int j = tid; j < 1024; j += 256) { lWlin[j] = Wlin[j]; lWprod[j] = Wprod[j]; lWup[j] = Wup_next[j]; }
    for (int j = tid; j < 2176; j += 256) lWsym[j] = WsymG[j];
    __syncthreads();

    int wave = tid >> 6, lane = tid & 63;
    int n = blockIdx.x * 4 + wave;
    int k0 = lane & 15, tq = lane >> 4;
    float* nb = buf + wave*NBSTRIDE;

    int start = row_ptr[n], end = row_ptr[n+1];
    float4 acc0 = {0,0,0,0}, acc1 = {0,0,0,0};

    if (start < end) {
        int snd = snd_csr[start];
        float4 c0v = *(const float4*)(C0c + (size_t)start*16 + tq*4);
        float rw0 = Rwc[(size_t)start*32 + k0];
        float rw1 = Rwc[(size_t)start*32 + 16 + k0];
        float u0 = up0c[(size_t)snd*32 + k0];
        float u1 = up0c[(size_t)snd*32 + 16 + k0];

        for (int ii = start; ii < end; ++ii) {
            int ip = (ii + 1 < end) ? ii + 1 : ii;
            int nsnd = snd_csr[ip];
            float4 nc0v = *(const float4*)(C0c + (size_t)ip*16 + tq*4);
            float nrw0 = Rwc[(size_t)ip*32 + k0];
            float nrw1 = Rwc[(size_t)ip*32 + 16 + k0];
            float nu0 = up0c[(size_t)nsnd*32 + k0];
            float nu1 = up0c[(size_t)nsnd*32 + 16 + k0];

            float g0 = rw0 * u0, g1 = rw1 * u1;
            acc0.x += g0*c0v.x; acc0.y += g0*c0v.y; acc0.z += g0*c0v.z; acc0.w += g0*c0v.w;
            acc1.x += g1*c0v.x; acc1.y += g1*c0v.y; acc1.z += g1*c0v.z; acc1.w += g1*c0v.w;

            c0v = nc0v; rw0 = nrw0; rw1 = nrw1; u0 = nu0; u1 = nu1;
        }
    }

    // agg -> nb rows (k0 covers rows k0 and 16+k0; cols tq*4..tq*4+3)
    *(float4*)(nb + k0*20 + tq*4)      = make_float4(acc0.x*0.0625f, acc0.y*0.0625f,
                                                     acc0.z*0.0625f, acc0.w*0.0625f);
    *(float4*)(nb + (16+k0)*20 + tq*4) = make_float4(acc1.x*0.0625f, acc1.y*0.0625f,
                                                     acc1.z*0.0625f, acc1.w*0.0625f);
    WAVE_SYNC();

    node_update(nb, lWlin, lWprod, lWup, lWsym, Wskip, feats, spec, out, n, lane, 0, up_next, 1);
}

// ---------------- layer 1 fused: fp16 MFMA aggregation (packed-f16 phase A) + node update ----------------
__global__ __launch_bounds__(256, 3) void k_fused1(const _Float16* __restrict__ up,
                                                   const float* __restrict__ Yc,
                                                   const float* __restrict__ Rwc,
                                                   const int* __restrict__ snd_csr,
                                                   const int* __restrict__ row_ptr,
                                                   const float* __restrict__ Wcg,
                                                   const float* __restrict__ Wlin,
                                                   const float* __restrict__ Wskip,
                                                   const float* __restrict__ Wprod,
                                                   const float* __restrict__ WsymG,
                                                   float* __restrict__ feats,
                                                   const int* __restrict__ spec,
                                                   float* __restrict__ out) {
    __shared__ __align__(16) float lWlin[1024];
    __shared__ __align__(16) float lWprod[1024];
    __shared__ __align__(16) float lWsym[2176];
    __shared__ __align__(16) float buf[4*NBSTRIDE];

    int tid = threadIdx.x;
    for (int j = tid; j < 1024; j += 256) { lWlin[j] = Wlin[j]; lWprod[j] = Wprod[j]; }
    for (int j = tid; j < 2176; j += 256) lWsym[j] = WsymG[j];
    __syncthreads();

    int wave = tid >> 6, lane = tid & 63;
    int n = blockIdx.x * 4 + wave;
    int t0 = lane & 15;
    int g  = lane >> 4;
    int h  = g & 1;
    int eo = g >> 1;
    float* nb = buf + wave*NBSTRIDE;

    // per-lane Wcg slice packed f16: wrh[s][q] = {Wcg[8h+2q][s][t0], Wcg[8h+2q+1][s][t0]}  (32 VGPR)
    half2v wrh[16][4];
#pragma unroll
    for (int s = 0; s < 16; ++s)
#pragma unroll
        for (int q = 0; q < 4; ++q) {
            half2v w;
            w[0] = (_Float16)Wcg[(8*h + 2*q    )*256 + s*16 + t0];
            w[1] = (_Float16)Wcg[(8*h + 2*q + 1)*256 + s*16 + t0];
            wrh[s][q] = w;
        }

    int start = row_ptr[n], end = row_ptr[n+1];
    f32x4 accL = {0.f,0.f,0.f,0.f}, accH = {0.f,0.f,0.f,0.f};

    if (start < end) {
        int i0 = start + eo;     bool v0 = i0 < end; int q0 = v0 ? i0 : start;
        int i1 = i0 + 2;         bool v1 = i1 < end; int q1 = v1 ? i1 : start;
        int i2 = i0 + 4;         bool v2 = i2 < end; int q2 = v2 ? i2 : start;
        int snd0 = snd_csr[q0], snd1 = snd_csr[q1];
        int snd2 = snd_csr[q2];

        const float4* Y4 = (const float4*)(Yc + (size_t)q0*16);
        float4 y0=Y4[0], y1=Y4[1], y2=Y4[2], y3=Y4[3];
        float rwL = v0 ? Rwc[(size_t)q0*32 + t0]      : 0.0f;
        float rwH = v0 ? Rwc[(size_t)q0*32 + 16 + t0] : 0.0f;
        half8 u0L = *(const half8*)(up + (size_t)snd0*512 + t0*16 + 8*h);
        half8 u0H = *(const half8*)(up + (size_t)snd0*512 + (16+t0)*16 + 8*h);
        half8 u1L = *(const half8*)(up + (size_t)snd1*512 + t0*16 + 8*h);
        half8 u1H = *(const half8*)(up + (size_t)snd1*512 + (16+t0)*16 + 8*h);

        int npair = (end - start + 1) >> 1;
        for (int p = 0; p < npair; ++p) {
            half8 u2L = *(const half8*)(up + (size_t)snd2*512 + t0*16 + 8*h);
            half8 u2H = *(const half8*)(up + (size_t)snd2*512 + (16+t0)*16 + 8*h);
            int in1 = start + 2*(p+1) + eo; bool vn1 = in1 < end; int qn1 = vn1 ? in1 : start;
            const float4* nY = (const float4*)(Yc + (size_t)qn1*16);
            float4 ny0=nY[0], ny1=nY[1], ny2=nY[2], ny3=nY[3];
            float nrwL = vn1 ? Rwc[(size_t)qn1*32 + t0]      : 0.0f;
            float nrwH = vn1 ? Rwc[(size_t)qn1*32 + 16 + t0] : 0.0f;
            int in3 = start + 2*(p+3) + eo; bool vn3 = in3 < end; int qn3 = vn3 ? in3 : start;
            int snd3 = snd_csr[qn3];

            // ---- phase A packed f16: ch[q] = sum_s (f16)y[s] * wrh[s][q] ----
            float yv[16] = {y0.x,y0.y,y0.z,y0.w, y1.x,y1.y,y1.z,y1.w,
                            y2.x,y2.y,y2.z,y2.w, y3.x,y3.y,y3.z,y3.w};
            half2v ch[4];
#pragma unroll
            for (int q = 0; q < 4; ++q) { half2v z; z[0]=(_Float16)0.f; z[1]=(_Float16)0.f; ch[q]=z; }
#pragma unroll
            for (int s = 0; s < 16; ++s) {
                _Float16 yh = (_Float16)yv[s];
                half2v yb; yb[0] = yh; yb[1] = yh;
#pragma unroll
                for (int q = 0; q < 4; ++q) ch[q] += yb * wrh[s][q];
            }
            half8 bf;
#pragma unroll
            for (int q = 0; q < 4; ++q) { bf[2*q] = ch[q][0]; bf[2*q+1] = ch[q][1]; }

            half8 rvL, rvH;
            _Float16 rwLh = (_Float16)rwL, rwHh = (_Float16)rwH;
#pragma unroll
            for (int j = 0; j < 8; ++j) { rvL[j] = rwLh; rvH[j] = rwHh; }
            half8 afL = u0L * rvL;
            half8 afH = u0H * rvH;

            accL = __builtin_amdgcn_mfma_f32_16x16x32_f16(afL, bf, accL, 0, 0, 0);
            accH = __builtin_amdgcn_mfma_f32_16x16x32_f16(afH, bf, accH, 0, 0, 0);

            y0=ny0; y1=ny1; y2=ny2; y3=ny3;
            rwL=nrwL; rwH=nrwH;
            u0L=u1L; u0H=u1H; u1L=u2L; u1H=u2H;
            snd2 = snd3;
        }
    }

    // agg (MFMA D layout) -> nb rows: D row i=4g+e, col t0
#pragma unroll
    for (int e = 0; e < 4; ++e) {
        nb[(4*g + e)*20 + t0]      = accL[e] * 0.0625f;
        nb[(16 + 4*g + e)*20 + t0] = accH[e] * 0.0625f;
    }
    WAVE_SYNC();

    node_update(nb, lWlin, lWprod, (const float*)nullptr, lWsym, Wskip, feats, spec, out,
                n, lane, 1, (_Float16*)nullptr, 0);
}

extern "C" void kernel_launch(void* const* d_in, const int* in_sizes, int n_in,
                              void* d_out, int out_size, void* d_ws, size_t ws_size,
                              hipStream_t stream) {
    const float* pos     = (const float*)d_in[0];
    const float* shifts  = (const float*)d_in[1];
    const float* attrs   = (const float*)d_in[2];
    const float* W_embed = (const float*)d_in[3];
    const float* W_up    = (const float*)d_in[4];
    const float* W_r1    = (const float*)d_in[5];
    const float* W_r2    = (const float*)d_in[6];
    const float* W_lin   = (const float*)d_in[7];
    const float* W_skip  = (const float*)d_in[8];
    const float* W_prod  = (const float*)d_in[9];
    const float* Wcg     = (const float*)d_in[10];
    const float* Wcg2    = (const float*)d_in[11];
    const int*   ei      = (const int*)d_in[12];
    float* out = (float*)d_out;

    uint8_t* p = (uint8_t*)d_ws;
    auto alloc = [&](size_t bytes) -> void* {
        void* r = (void*)p;
        p += (bytes + 255) & ~size_t(255);
        return r;
    };
    float* Yc        = (float*)alloc((size_t)N_EDGES * 16 * sizeof(float));
    float* C0c       = (float*)alloc((size_t)N_EDGES * 16 * sizeof(float));
    float* Rwc0      = (float*)alloc((size_t)N_EDGES * K  * sizeof(float));
    float* Rwc1      = (float*)alloc((size_t)N_EDGES * K  * sizeof(float));
    float* feats     = (float*)alloc((size_t)N_NODES * K * LDIM * sizeof(float));
    _Float16* up_h   = (_Float16*)alloc((size_t)N_NODES * K * LDIM * sizeof(_Float16));
    float* up0c      = (float*)alloc((size_t)N_NODES * K * sizeof(float));
    float* WW        = (float*)alloc((size_t)NZ * K * sizeof(float));
    float* Wsym      = (float*)alloc((size_t)136 * 16 * sizeof(float));
    int* counts   = (int*)alloc((size_t)N_NODES * sizeof(int));
    int* woff     = (int*)alloc((size_t)N_NODES * sizeof(int));
    int* row_ptr  = (int*)alloc((size_t)(N_NODES + 1) * sizeof(int));
    int* inv      = (int*)alloc((size_t)N_EDGES * sizeof(int));
    int* snd_csr  = (int*)alloc((size_t)N_EDGES * sizeof(int));
    int* spec     = (int*)alloc((size_t)N_NODES * sizeof(int));

    hipMemsetAsync(counts, 0, N_NODES * sizeof(int), stream);
    k_count<<<(N_EDGES + 255) / 256, 256, 0, stream>>>(ei, counts);
    k_scan<<<1, 1024, 0, stream>>>(counts, row_ptr, woff);
    k_scatter<<<(N_EDGES + 255) / 256, 256, 0, stream>>>(ei, woff, inv, snd_csr);
    k_geom<<<(N_EDGES + 255) / 256, 256, 0, stream>>>(pos, shifts, ei, inv, Wcg,
                                                      W_r1, W_r2, Yc, C0c, Rwc0, Rwc1);
    k_ww<<<2, 256, 0, stream>>>(W_embed, W_up, WW);
    k_wsym<<<(136*16 + 255) / 256, 256, 0, stream>>>(Wcg2, Wsym);
    k_embed<<<(N_NODES * K + 255) / 256, 256, 0, stream>>>(attrs, W_embed, WW, feats, up0c, spec);

    // layer 0 fused (writes out[:,0:32], feats, up_h for layer 1)
    k_fused0<<<N_NODES/4, 256, 0, stream>>>(up0c, C0c, Rwc0, snd_csr, row_ptr,
                                            W_lin, W_skip, W_prod, Wsym,
                                            W_up + (size_t)1*K*K,
                                            feats, spec, out, up_h);

    // layer 1 fused (writes out[:,32:64], feats)
    k_fused1<<<N_NODES/4, 256, 0, stream>>>(up_h, Yc, Rwc1, snd_csr, row_ptr, Wcg,
                                            W_lin + (size_t)1*K*K,
                                            W_skip + (size_t)1*NZ*K*K,
                                            W_prod + (size_t)1*K*K, Wsym,
                                            feats, spec, out);
}